// Round 3
// baseline (416.995 us; speedup 1.0000x reference)
//
#include <hip/hip_runtime.h>
#include <hip/hip_bf16.h>

typedef unsigned short u16;
typedef __attribute__((ext_vector_type(8))) short short8;
typedef __attribute__((ext_vector_type(4))) float f32x4;
typedef __attribute__((ext_vector_type(4))) unsigned short u16x4;

#define SEQ 2048
#define NH 16
#define HD 64
#define DM 1024
#define LN_DECAY (-0.051293294387550536f)

__device__ __forceinline__ float b2f(u16 u) {
    return __uint_as_float(((unsigned int)u) << 16);
}
__device__ __forceinline__ u16 f2b(float f) {
    unsigned int u = __float_as_uint(f);
    u += 0x7fffu + ((u >> 16) & 1u);   // round-to-nearest-even
    return (u16)(u >> 16);
}
__device__ __forceinline__ f32x4 mfma16(short8 a, short8 b, f32x4 c) {
    return __builtin_amdgcn_mfma_f32_16x16x32_bf16(a, b, c, 0, 0, 0);
}

// ---------------- dtype detection ----------------
// If the buffer holds fp32, even-index u16s are low mantissa words: their
// bf16-exponent field is uniform -> some sample exceeds 0xC0 w.p. 1-1e-32.
// If it holds bf16 N(0,1/32) weights, exponent <= 124 always.
__global__ __launch_bounds__(64) void detect_dtype(const u16* __restrict__ W,
                                                   int* __restrict__ flag) {
    int t = threadIdx.x;
    int hit = 0;
    for (int i = t; i < 512; i += 64) {
        u16 u = W[2 * i];
        int e = (u >> 7) & 0xFF;
        if (e >= 0xC0) hit = 1;
    }
    unsigned long long m = __ballot(hit);
    if (t == 0) *flag = (m != 0ULL) ? 1 : 0;
}

// ---------------- input canonicalization to bf16 ----------------
__global__ __launch_bounds__(256) void convert_x(const void* __restrict__ x,
                                                 const int* __restrict__ flag,
                                                 u16* __restrict__ xc) {
    int i = (blockIdx.x * 256 + threadIdx.x) * 4;
    if (*flag) {
        f32x4 v = *(const f32x4*)((const float*)x + i);
        u16x4 o = { f2b(v[0]), f2b(v[1]), f2b(v[2]), f2b(v[3]) };
        *(u16x4*)(xc + i) = o;
    } else {
        *(u16x4*)(xc + i) = *(const u16x4*)((const u16*)x + i);
    }
}

__global__ __launch_bounds__(256) void convert_small(
    const void* __restrict__ p0, const void* __restrict__ p1,
    const void* __restrict__ p2, const void* __restrict__ p3,
    const void* __restrict__ p4, const void* __restrict__ p5,
    const int* __restrict__ flag,
    u16* __restrict__ o0, u16* __restrict__ o1, u16* __restrict__ o2,
    u16* __restrict__ o3, u16* __restrict__ o4, u16* __restrict__ o5) {
    const void* in; u16* out;
    switch (blockIdx.x) {
        case 0: in = p0; out = o0; break;
        case 1: in = p1; out = o1; break;
        case 2: in = p2; out = o2; break;
        case 3: in = p3; out = o3; break;
        case 4: in = p4; out = o4; break;
        default: in = p5; out = o5; break;
    }
    int i = threadIdx.x * 4;
    if (*flag) {
        f32x4 v = *(const f32x4*)((const float*)in + i);
        u16x4 o = { f2b(v[0]), f2b(v[1]), f2b(v[2]), f2b(v[3]) };
        *(u16x4*)(out + i) = o;
    } else {
        *(u16x4*)(out + i) = *(const u16x4*)((const u16*)in + i);
    }
}

// ---------------- weight transpose+convert: W[k][n] -> WT[n][k] bf16 -------
__global__ __launch_bounds__(256) void transpose4(
    const void* __restrict__ W0, const void* __restrict__ W1,
    const void* __restrict__ W2, const void* __restrict__ W3,
    const int* __restrict__ flag,
    u16* __restrict__ T0, u16* __restrict__ T1,
    u16* __restrict__ T2, u16* __restrict__ T3)
{
    __shared__ u16 tile[32][33];
    const void* W; u16* T;
    int z = blockIdx.z;
    if (z == 0)      { W = W0; T = T0; }
    else if (z == 1) { W = W1; T = T1; }
    else if (z == 2) { W = W2; T = T2; }
    else             { W = W3; T = T3; }
    int fl = *flag;
    int t = threadIdx.x;
    int r = t >> 5, c = t & 31;
    int bn = blockIdx.x * 32, bk = blockIdx.y * 32;
#pragma unroll
    for (int i = 0; i < 4; i++) {
        size_t idx = (size_t)(bk + r + i*8) * DM + bn + c;
        tile[r + i*8][c] = fl ? f2b(((const float*)W)[idx]) : ((const u16*)W)[idx];
    }
    __syncthreads();
#pragma unroll
    for (int i = 0; i < 4; i++)
        T[(size_t)(bn + r + i*8) * DM + bk + c] = tile[c][r + i*8];
}

// ---------------- 128x128 MFMA GEMM body ----------------
__device__ __forceinline__ void gemm_body(
    const u16* __restrict__ A, const u16* __restrict__ BT,
    const u16* __restrict__ bias, u16* __restrict__ outB,
    float* __restrict__ outF, int mode,
    int m0, int n0, int t)
{
    __shared__ u16 As[128][40];
    __shared__ u16 Bs[128][40];
    int w = t >> 6, l = t & 63;
    int lane16 = l & 15, quad = l >> 4;
    int wm = (w >> 1) * 64, wn = (w & 1) * 64;
    int lr = t >> 2, lu = t & 3;

    f32x4 zero = {0.f, 0.f, 0.f, 0.f};
    f32x4 acc[4][4];
#pragma unroll
    for (int i = 0; i < 4; i++)
#pragma unroll
        for (int j = 0; j < 4; j++)
            acc[i][j] = zero;

    for (int k0 = 0; k0 < DM; k0 += 32) {
        __syncthreads();
        *(short8*)(&As[lr][lu*8])      = *(const short8*)(A  + (size_t)(m0+lr)   *DM + k0 + lu*8);
        *(short8*)(&As[lr+64][lu*8])   = *(const short8*)(A  + (size_t)(m0+lr+64)*DM + k0 + lu*8);
        *(short8*)(&Bs[lr][lu*8])      = *(const short8*)(BT + (size_t)(n0+lr)   *DM + k0 + lu*8);
        *(short8*)(&Bs[lr+64][lu*8])   = *(const short8*)(BT + (size_t)(n0+lr+64)*DM + k0 + lu*8);
        __syncthreads();
        short8 af[4], bf[4];
#pragma unroll
        for (int i = 0; i < 4; i++) {
            af[i] = *(const short8*)(&As[wm + i*16 + lane16][quad*8]);
            bf[i] = *(const short8*)(&Bs[wn + i*16 + lane16][quad*8]);
        }
#pragma unroll
        for (int i = 0; i < 4; i++)
#pragma unroll
            for (int j = 0; j < 4; j++)
                acc[i][j] = mfma16(af[i], bf[j], acc[i][j]);
    }

#pragma unroll
    for (int i = 0; i < 4; i++) {
#pragma unroll
        for (int j = 0; j < 4; j++) {
            int n = n0 + wn + j*16 + lane16;
            float bv = b2f(bias[n]);
#pragma unroll
            for (int r = 0; r < 4; r++) {
                int m = m0 + wm + i*16 + quad*4 + r;
                float v = acc[i][j][r] + bv;
                if (mode == 3) {
                    outF[(size_t)m*DM + n] = v;
                } else {
                    int b = m >> 11, s = m & (SEQ-1);
                    int h = n >> 6,  d = n & (HD-1);
                    if (mode == 2)
                        outB[(((size_t)(b*NH + h))*HD + d)*SEQ + s] = f2b(v);
                    else
                        outB[(((size_t)(b*NH + h))*SEQ + s)*HD + d] = f2b(v);
                }
            }
        }
    }
}

__global__ __launch_bounds__(256) void gemm_qkv(
    const u16* __restrict__ x,
    const u16* __restrict__ WqT, const u16* __restrict__ WkT, const u16* __restrict__ WvT,
    const u16* __restrict__ bq, const u16* __restrict__ bk, const u16* __restrict__ bv,
    u16* __restrict__ qb, u16* __restrict__ kb, u16* __restrict__ vTb)
{
    int z = blockIdx.z;
    const u16* BT   = (z==0) ? WqT : (z==1) ? WkT : WvT;
    const u16* bias = (z==0) ? bq  : (z==1) ? bk  : bv;
    u16* outB       = (z==0) ? qb  : (z==1) ? kb  : vTb;
    gemm_body(x, BT, bias, outB, nullptr, (z==2) ? 2 : 0,
              blockIdx.x * 128, blockIdx.y * 128, threadIdx.x);
}

__global__ __launch_bounds__(256) void gemm_out(
    const u16* __restrict__ attn, const u16* __restrict__ WoT,
    const u16* __restrict__ bo, float* __restrict__ proj)
{
    gemm_body(attn, WoT, bo, nullptr, proj, 3,
              blockIdx.x * 128, blockIdx.y * 128, threadIdx.x);
}

// ---------------- retention: out = (QK^T * decay_mask) @ V ----------------
__global__ __launch_bounds__(256) void retention(
    const u16* __restrict__ q, const u16* __restrict__ k,
    const u16* __restrict__ vT, u16* __restrict__ attn)
{
    __shared__ u16 Ks[64][72];
    __shared__ u16 Vs[64][72];
    __shared__ u16 Ps[4][16][72];   // per-wave P tile, bf16

    int qt = blockIdx.x, bh = blockIdx.y;
    int t = threadIdx.x, w = t >> 6, l = t & 63;
    int lane16 = l & 15, quad = l >> 4;
    int qbase = qt * 64;
    int sr = t >> 3, sc = (t & 7) * 8;   // staging: 32 rows x 64 cols per pass

    const u16* qh = q  + (size_t)bh * SEQ * HD;
    const u16* kh = k  + (size_t)bh * SEQ * HD;
    const u16* vh = vT + (size_t)bh * HD * SEQ;

    int qrow = qbase + w*16 + lane16;
    short8 qf0 = *(const short8*)(qh + (size_t)qrow*HD + quad*8);
    short8 qf1 = *(const short8*)(qh + (size_t)qrow*HD + 32 + quad*8);

    f32x4 zero = {0.f, 0.f, 0.f, 0.f};
    f32x4 oacc[4] = {zero, zero, zero, zero};

    for (int jt = 0; jt <= qt; jt++) {
        int jbase = jt * 64;
        __syncthreads();
        *(short8*)(&Ks[sr][sc])    = *(const short8*)(kh + (size_t)(jbase + sr)*HD + sc);
        *(short8*)(&Ks[sr+32][sc]) = *(const short8*)(kh + (size_t)(jbase + sr + 32)*HD + sc);
        *(short8*)(&Vs[sr][sc])    = *(const short8*)(vh + (size_t)sr*SEQ + jbase + sc);
        *(short8*)(&Vs[sr+32][sc]) = *(const short8*)(vh + (size_t)(sr + 32)*SEQ + jbase + sc);
        __syncthreads();

        // S = q @ k^T  (C layout: row=i=quad*4+reg, col=j=lane16)
        f32x4 sacc[4] = {zero, zero, zero, zero};
#pragma unroll
        for (int st = 0; st < 4; st++) {
            short8 b0 = *(const short8*)(&Ks[st*16 + lane16][quad*8]);
            short8 b1 = *(const short8*)(&Ks[st*16 + lane16][32 + quad*8]);
            sacc[st] = mfma16(qf0, b0, sacc[st]);
            sacc[st] = mfma16(qf1, b1, sacc[st]);
        }
        // decay mask, write P (bf16) to per-wave LDS (C-layout -> A-layout)
        int ibase = qbase + w*16 + quad*4;
#pragma unroll
        for (int st = 0; st < 4; st++) {
            int j = jbase + st*16 + lane16;
#pragma unroll
            for (int r = 0; r < 4; r++) {
                int i = ibase + r;
                float wgt = (i >= j) ? __expf((float)(i - j) * LN_DECAY) : 0.0f;
                Ps[w][quad*4 + r][st*16 + lane16] = f2b(sacc[st][r] * wgt);
            }
        }
        asm volatile("s_waitcnt lgkmcnt(0)" ::: "memory");
        short8 pf0 = *(const short8*)(&Ps[w][lane16][quad*8]);
        short8 pf1 = *(const short8*)(&Ps[w][lane16][32 + quad*8]);
        // O += P @ V   (B operand from vT: [n=d][k=j])
#pragma unroll
        for (int nt = 0; nt < 4; nt++) {
            short8 v0 = *(const short8*)(&Vs[nt*16 + lane16][quad*8]);
            short8 v1 = *(const short8*)(&Vs[nt*16 + lane16][32 + quad*8]);
            oacc[nt] = mfma16(pf0, v0, oacc[nt]);
            oacc[nt] = mfma16(pf1, v1, oacc[nt]);
        }
    }

    int b = bh >> 4, h = bh & (NH-1);
#pragma unroll
    for (int nt = 0; nt < 4; nt++) {
        int d = h*HD + nt*16 + lane16;
#pragma unroll
        for (int r = 0; r < 4; r++) {
            int s = qbase + w*16 + quad*4 + r;
            attn[((size_t)(b*SEQ + s))*DM + d] = f2b(oacc[nt][r]);
        }
    }
}

// ---------------- GroupNorm ----------------
__global__ __launch_bounds__(256) void gn_stats(
    const float* __restrict__ proj, float* __restrict__ stats)
{
    int bg = blockIdx.x;              // 0..31 : (b,g)
    int b = bg >> 4, g = bg & (NH-1);
    const float* base = proj + (size_t)b*SEQ*DM + g*HD;
    float s = 0.f, ss = 0.f;
    for (int idx = threadIdx.x; idx < SEQ*HD; idx += 256) {
        int sr = idx >> 6, d = idx & (HD-1);
        float v = base[(size_t)sr*DM + d];
        s += v; ss += v*v;
    }
#pragma unroll
    for (int off = 32; off > 0; off >>= 1) {
        s  += __shfl_down(s, off);
        ss += __shfl_down(ss, off);
    }
    __shared__ float red[8];
    int w = threadIdx.x >> 6, l = threadIdx.x & 63;
    if (l == 0) { red[w*2] = s; red[w*2+1] = ss; }
    __syncthreads();
    if (threadIdx.x == 0) {
        float S  = red[0]+red[2]+red[4]+red[6];
        float SS = red[1]+red[3]+red[5]+red[7];
        const float inv = 1.0f / (float)(SEQ*HD);
        float mu = S * inv;
        float var = SS * inv - mu*mu;
        stats[bg*2]   = mu;
        stats[bg*2+1] = rsqrtf(var + 1e-5f);
    }
}

__global__ __launch_bounds__(256) void gn_apply(
    const float* __restrict__ proj, const float* __restrict__ stats,
    const u16* __restrict__ gamma, const u16* __restrict__ beta,
    const int* __restrict__ flag, void* __restrict__ outv)
{
    int idx = blockIdx.x * 256 + threadIdx.x;  // over B*S*D = 4M
    int d = idx & (DM-1);
    int bs = idx >> 10;
    int b = bs >> 11;
    int g = d >> 6;
    float mu   = stats[(b*NH + g)*2];
    float rstd = stats[(b*NH + g)*2 + 1];
    float v = (proj[idx] - mu) * rstd * b2f(gamma[d]) + b2f(beta[d]);
    if (*flag) ((float*)outv)[idx] = v;
    else       ((u16*)outv)[idx]   = f2b(v);
}

// ---------------- launch ----------------
extern "C" void kernel_launch(void* const* d_in, const int* in_sizes, int n_in,
                              void* d_out, int out_size, void* d_ws, size_t ws_size,
                              hipStream_t stream) {
    const void* x     = d_in[0];
    const void* Wq    = d_in[1];
    const void* bq    = d_in[2];
    const void* Wk    = d_in[3];
    const void* bk    = d_in[4];
    const void* Wv    = d_in[5];
    const void* bv    = d_in[6];
    const void* Wo    = d_in[7];
    const void* bo    = d_in[8];
    const void* gamma = d_in[9];
    const void* beta  = d_in[10];

    const size_t MB = 1024*1024;
    char* ws = (char*)d_ws;
    int*   flag   = (int*)ws;
    u16*   bqc    = (u16*)(ws + 4096);
    u16*   bkc    = (u16*)(ws + 8192);
    u16*   bvc    = (u16*)(ws + 12288);
    u16*   boc    = (u16*)(ws + 16384);
    u16*   gammac = (u16*)(ws + 20480);
    u16*   betac  = (u16*)(ws + 24576);
    float* stats  = (float*)(ws + 28672);
    u16*   xc     = (u16*)(ws + 1*MB);    // 8 MB
    u16*   WqT    = (u16*)(ws + 9*MB);
    u16*   WkT    = (u16*)(ws + 11*MB);
    u16*   WvT    = (u16*)(ws + 13*MB);
    u16*   WoT    = (u16*)(ws + 15*MB);
    u16*   qb     = (u16*)(ws + 17*MB);   // 8 MB
    u16*   kb     = (u16*)(ws + 25*MB);   // 8 MB
    u16*   vTb    = (u16*)(ws + 33*MB);   // 8 MB
    u16*   attn   = (u16*)(ws + 41*MB);   // 8 MB
    float* proj   = (float*)(ws + 17*MB); // 16 MB, overlays qb/kb (free after retention)

    detect_dtype<<<1, 64, 0, stream>>>((const u16*)Wq, flag);
    convert_x<<<4096, 256, 0, stream>>>(x, flag, xc);
    convert_small<<<6, 256, 0, stream>>>(bq, bk, bv, bo, gamma, beta, flag,
                                         bqc, bkc, bvc, boc, gammac, betac);
    transpose4<<<dim3(32, 32, 4), 256, 0, stream>>>(Wq, Wk, Wv, Wo, flag, WqT, WkT, WvT, WoT);
    gemm_qkv<<<dim3(32, 8, 3), 256, 0, stream>>>(xc, WqT, WkT, WvT, bqc, bkc, bvc, qb, kb, vTb);
    retention<<<dim3(32, 32), 256, 0, stream>>>(qb, kb, vTb, attn);
    gemm_out<<<dim3(32, 8), 256, 0, stream>>>(attn, WoT, boc, proj);
    gn_stats<<<32, 256, 0, stream>>>(proj, stats);
    gn_apply<<<(SEQ*DM*2)/256, 256, 0, stream>>>(proj, stats, gammac, betac, flag, d_out);
}

// Round 4
// 268.371 us; speedup vs baseline: 1.5538x; 1.5538x over previous
//
#include <hip/hip_runtime.h>
#include <hip/hip_bf16.h>

typedef unsigned short u16;
typedef __attribute__((ext_vector_type(8))) short short8;
typedef __attribute__((ext_vector_type(4))) float f32x4;
typedef __attribute__((ext_vector_type(4))) unsigned short u16x4;

#define SEQ 2048
#define NH 16
#define HD 64
#define DM 1024
#define LN_DECAY (-0.051293294387550536f)

__device__ __forceinline__ float b2f(u16 u) {
    return __uint_as_float(((unsigned int)u) << 16);
}
__device__ __forceinline__ u16 f2b(float f) {
    unsigned int u = __float_as_uint(f);
    u += 0x7fffu + ((u >> 16) & 1u);   // round-to-nearest-even
    return (u16)(u >> 16);
}
__device__ __forceinline__ f32x4 mfma16(short8 a, short8 b, f32x4 c) {
    return __builtin_amdgcn_mfma_f32_16x16x32_bf16(a, b, c, 0, 0, 0);
}

// ---------------- dtype detection ----------------
__global__ __launch_bounds__(64) void detect_dtype(const u16* __restrict__ W,
                                                   int* __restrict__ flag) {
    int t = threadIdx.x;
    int hit = 0;
    for (int i = t; i < 512; i += 64) {
        u16 u = W[2 * i];
        int e = (u >> 7) & 0xFF;
        if (e >= 0xC0) hit = 1;
    }
    unsigned long long m = __ballot(hit);
    if (t == 0) *flag = (m != 0ULL) ? 1 : 0;
}

// ---------------- input canonicalization to bf16 ----------------
__global__ __launch_bounds__(256) void convert_x(const void* __restrict__ x,
                                                 const int* __restrict__ flag,
                                                 u16* __restrict__ xc) {
    int i = (blockIdx.x * 256 + threadIdx.x) * 4;
    if (*flag) {
        f32x4 v = *(const f32x4*)((const float*)x + i);
        u16x4 o = { f2b(v[0]), f2b(v[1]), f2b(v[2]), f2b(v[3]) };
        *(u16x4*)(xc + i) = o;
    } else {
        *(u16x4*)(xc + i) = *(const u16x4*)((const u16*)x + i);
    }
}

__global__ __launch_bounds__(256) void convert_small(
    const void* __restrict__ p0, const void* __restrict__ p1,
    const void* __restrict__ p2, const void* __restrict__ p3,
    const void* __restrict__ p4, const void* __restrict__ p5,
    const int* __restrict__ flag,
    u16* __restrict__ o0, u16* __restrict__ o1, u16* __restrict__ o2,
    u16* __restrict__ o3, u16* __restrict__ o4, u16* __restrict__ o5) {
    const void* in; u16* out;
    switch (blockIdx.x) {
        case 0: in = p0; out = o0; break;
        case 1: in = p1; out = o1; break;
        case 2: in = p2; out = o2; break;
        case 3: in = p3; out = o3; break;
        case 4: in = p4; out = o4; break;
        default: in = p5; out = o5; break;
    }
    int i = threadIdx.x * 4;
    if (*flag) {
        f32x4 v = *(const f32x4*)((const float*)in + i);
        u16x4 o = { f2b(v[0]), f2b(v[1]), f2b(v[2]), f2b(v[3]) };
        *(u16x4*)(out + i) = o;
    } else {
        *(u16x4*)(out + i) = *(const u16x4*)((const u16*)in + i);
    }
}

// ---------------- weight transpose+convert: W[k][n] -> WT[n][k] bf16 -------
__global__ __launch_bounds__(256) void transpose4(
    const void* __restrict__ W0, const void* __restrict__ W1,
    const void* __restrict__ W2, const void* __restrict__ W3,
    const int* __restrict__ flag,
    u16* __restrict__ T0, u16* __restrict__ T1,
    u16* __restrict__ T2, u16* __restrict__ T3)
{
    __shared__ u16 tile[32][33];
    const void* W; u16* T;
    int z = blockIdx.z;
    if (z == 0)      { W = W0; T = T0; }
    else if (z == 1) { W = W1; T = T1; }
    else if (z == 2) { W = W2; T = T2; }
    else             { W = W3; T = T3; }
    int fl = *flag;
    int t = threadIdx.x;
    int r = t >> 5, c = t & 31;
    int bn = blockIdx.x * 32, bk = blockIdx.y * 32;
#pragma unroll
    for (int i = 0; i < 4; i++) {
        size_t idx = (size_t)(bk + r + i*8) * DM + bn + c;
        tile[r + i*8][c] = fl ? f2b(((const float*)W)[idx]) : ((const u16*)W)[idx];
    }
    __syncthreads();
#pragma unroll
    for (int i = 0; i < 4; i++)
        T[(size_t)(bn + r + i*8) * DM + bk + c] = tile[c][r + i*8];
}

// ---------------- 128x128 MFMA GEMM body ----------------
__device__ __forceinline__ void gemm_body(
    const u16* __restrict__ A, const u16* __restrict__ BT,
    const u16* __restrict__ bias, u16* __restrict__ outB,
    float* __restrict__ outF, int mode,
    int m0, int n0, int t)
{
    __shared__ u16 As[128][40];
    __shared__ u16 Bs[128][40];
    int w = t >> 6, l = t & 63;
    int lane16 = l & 15, quad = l >> 4;
    int wm = (w >> 1) * 64, wn = (w & 1) * 64;
    int lr = t >> 2, lu = t & 3;

    f32x4 zero = {0.f, 0.f, 0.f, 0.f};
    f32x4 acc[4][4];
#pragma unroll
    for (int i = 0; i < 4; i++)
#pragma unroll
        for (int j = 0; j < 4; j++)
            acc[i][j] = zero;

    for (int k0 = 0; k0 < DM; k0 += 32) {
        __syncthreads();
        *(short8*)(&As[lr][lu*8])      = *(const short8*)(A  + (size_t)(m0+lr)   *DM + k0 + lu*8);
        *(short8*)(&As[lr+64][lu*8])   = *(const short8*)(A  + (size_t)(m0+lr+64)*DM + k0 + lu*8);
        *(short8*)(&Bs[lr][lu*8])      = *(const short8*)(BT + (size_t)(n0+lr)   *DM + k0 + lu*8);
        *(short8*)(&Bs[lr+64][lu*8])   = *(const short8*)(BT + (size_t)(n0+lr+64)*DM + k0 + lu*8);
        __syncthreads();
        short8 af[4], bf[4];
#pragma unroll
        for (int i = 0; i < 4; i++) {
            af[i] = *(const short8*)(&As[wm + i*16 + lane16][quad*8]);
            bf[i] = *(const short8*)(&Bs[wn + i*16 + lane16][quad*8]);
        }
#pragma unroll
        for (int i = 0; i < 4; i++)
#pragma unroll
            for (int j = 0; j < 4; j++)
                acc[i][j] = mfma16(af[i], bf[j], acc[i][j]);
    }

#pragma unroll
    for (int i = 0; i < 4; i++) {
#pragma unroll
        for (int j = 0; j < 4; j++) {
            int n = n0 + wn + j*16 + lane16;
            float bv = b2f(bias[n]);
#pragma unroll
            for (int r = 0; r < 4; r++) {
                int m = m0 + wm + i*16 + quad*4 + r;
                float v = acc[i][j][r] + bv;
                if (mode == 3) {
                    outF[(size_t)m*DM + n] = v;
                } else {
                    int b = m >> 11, s = m & (SEQ-1);
                    int h = n >> 6,  d = n & (HD-1);
                    if (mode == 2)
                        outB[(((size_t)(b*NH + h))*HD + d)*SEQ + s] = f2b(v);
                    else
                        outB[(((size_t)(b*NH + h))*SEQ + s)*HD + d] = f2b(v);
                }
            }
        }
    }
}

__global__ __launch_bounds__(256) void gemm_qkv(
    const u16* __restrict__ x,
    const u16* __restrict__ WqT, const u16* __restrict__ WkT, const u16* __restrict__ WvT,
    const u16* __restrict__ bq, const u16* __restrict__ bk, const u16* __restrict__ bv,
    u16* __restrict__ qb, u16* __restrict__ kb, u16* __restrict__ vTb)
{
    int z = blockIdx.z;
    const u16* BT   = (z==0) ? WqT : (z==1) ? WkT : WvT;
    const u16* bias = (z==0) ? bq  : (z==1) ? bk  : bv;
    u16* outB       = (z==0) ? qb  : (z==1) ? kb  : vTb;
    gemm_body(x, BT, bias, outB, nullptr, (z==2) ? 2 : 0,
              blockIdx.x * 128, blockIdx.y * 128, threadIdx.x);
}

__global__ __launch_bounds__(256) void gemm_out(
    const u16* __restrict__ attn, const u16* __restrict__ WoT,
    const u16* __restrict__ bo, float* __restrict__ proj)
{
    gemm_body(attn, WoT, bo, nullptr, proj, 3,
              blockIdx.x * 128, blockIdx.y * 128, threadIdx.x);
}

// ---------------- retention: out = (QK^T * decay_mask) @ V ----------------
__global__ __launch_bounds__(256) void retention(
    const u16* __restrict__ q, const u16* __restrict__ k,
    const u16* __restrict__ vT, u16* __restrict__ attn)
{
    __shared__ u16 Ks[64][72];
    __shared__ u16 Vs[64][72];
    __shared__ u16 Ps[4][16][72];   // per-wave P tile, bf16

    int qt = blockIdx.x, bh = blockIdx.y;
    int t = threadIdx.x, w = t >> 6, l = t & 63;
    int lane16 = l & 15, quad = l >> 4;
    int qbase = qt * 64;
    int sr = t >> 3, sc = (t & 7) * 8;   // staging: 32 rows x 64 cols per pass

    const u16* qh = q  + (size_t)bh * SEQ * HD;
    const u16* kh = k  + (size_t)bh * SEQ * HD;
    const u16* vh = vT + (size_t)bh * HD * SEQ;

    int qrow = qbase + w*16 + lane16;
    short8 qf0 = *(const short8*)(qh + (size_t)qrow*HD + quad*8);
    short8 qf1 = *(const short8*)(qh + (size_t)qrow*HD + 32 + quad*8);

    f32x4 zero = {0.f, 0.f, 0.f, 0.f};
    f32x4 oacc[4] = {zero, zero, zero, zero};

    for (int jt = 0; jt <= qt; jt++) {
        int jbase = jt * 64;
        __syncthreads();
        *(short8*)(&Ks[sr][sc])    = *(const short8*)(kh + (size_t)(jbase + sr)*HD + sc);
        *(short8*)(&Ks[sr+32][sc]) = *(const short8*)(kh + (size_t)(jbase + sr + 32)*HD + sc);
        *(short8*)(&Vs[sr][sc])    = *(const short8*)(vh + (size_t)sr*SEQ + jbase + sc);
        *(short8*)(&Vs[sr+32][sc]) = *(const short8*)(vh + (size_t)(sr + 32)*SEQ + jbase + sc);
        __syncthreads();

        // S = q @ k^T  (C layout: row=i=quad*4+reg, col=j=lane16)
        f32x4 sacc[4] = {zero, zero, zero, zero};
#pragma unroll
        for (int st = 0; st < 4; st++) {
            short8 b0 = *(const short8*)(&Ks[st*16 + lane16][quad*8]);
            short8 b1 = *(const short8*)(&Ks[st*16 + lane16][32 + quad*8]);
            sacc[st] = mfma16(qf0, b0, sacc[st]);
            sacc[st] = mfma16(qf1, b1, sacc[st]);
        }
        // decay mask, write P (bf16) to per-wave LDS (C-layout -> A-layout)
        int ibase = qbase + w*16 + quad*4;
#pragma unroll
        for (int st = 0; st < 4; st++) {
            int j = jbase + st*16 + lane16;
#pragma unroll
            for (int r = 0; r < 4; r++) {
                int i = ibase + r;
                float wgt = (i >= j) ? __expf((float)(i - j) * LN_DECAY) : 0.0f;
                Ps[w][quad*4 + r][st*16 + lane16] = f2b(sacc[st][r] * wgt);
            }
        }
        asm volatile("s_waitcnt lgkmcnt(0)" ::: "memory");
        short8 pf0 = *(const short8*)(&Ps[w][lane16][quad*8]);
        short8 pf1 = *(const short8*)(&Ps[w][lane16][32 + quad*8]);
        // O += P @ V   (B operand from vT: [n=d][k=j])
#pragma unroll
        for (int nt = 0; nt < 4; nt++) {
            short8 v0 = *(const short8*)(&Vs[nt*16 + lane16][quad*8]);
            short8 v1 = *(const short8*)(&Vs[nt*16 + lane16][32 + quad*8]);
            oacc[nt] = mfma16(pf0, v0, oacc[nt]);
            oacc[nt] = mfma16(pf1, v1, oacc[nt]);
        }
    }

    int b = bh >> 4, h = bh & (NH-1);
#pragma unroll
    for (int nt = 0; nt < 4; nt++) {
        int d = h*HD + nt*16 + lane16;
#pragma unroll
        for (int r = 0; r < 4; r++) {
            int s = qbase + w*16 + quad*4 + r;
            attn[((size_t)(b*SEQ + s))*DM + d] = f2b(oacc[nt][r]);
        }
    }
}

// ---------------- GroupNorm stats: two-stage reduction ----------------
// Stage 1: 32 (b,g) groups x 16 seq-chunks = 512 blocks, coalesced float4.
__global__ __launch_bounds__(256) void gn_partial(
    const float* __restrict__ proj, float* __restrict__ partials)
{
    int bg = blockIdx.x;              // 0..31 : (b,g)
    int chunk = blockIdx.y;           // 0..15 : seq chunk of 128 rows
    int b = bg >> 4, g = bg & (NH-1);
    const float* base = proj + (size_t)b*SEQ*DM + g*HD;
    int tid = threadIdx.x;
    int rlane = tid & 15;             // float4 slot within group row (16*4=64)
    int rrow  = tid >> 4;             // 0..15
    float s = 0.f, ss = 0.f;
#pragma unroll
    for (int it = 0; it < 8; it++) {
        int srow = chunk*128 + it*16 + rrow;
        f32x4 v = *(const f32x4*)(base + (size_t)srow*DM + rlane*4);
        s  += v[0] + v[1] + v[2] + v[3];
        ss += v[0]*v[0] + v[1]*v[1] + v[2]*v[2] + v[3]*v[3];
    }
#pragma unroll
    for (int off = 32; off > 0; off >>= 1) {
        s  += __shfl_down(s, off);
        ss += __shfl_down(ss, off);
    }
    __shared__ float red[8];
    int w = tid >> 6, l = tid & 63;
    if (l == 0) { red[w*2] = s; red[w*2+1] = ss; }
    __syncthreads();
    if (tid == 0) {
        float S  = red[0]+red[2]+red[4]+red[6];
        float SS = red[1]+red[3]+red[5]+red[7];
        partials[(bg*16 + chunk)*2]     = S;
        partials[(bg*16 + chunk)*2 + 1] = SS;
    }
}

// Stage 2: 32 blocks fold 16 partials -> (mu, rstd)
__global__ __launch_bounds__(64) void gn_finalize(
    const float* __restrict__ partials, float* __restrict__ stats)
{
    int bg = blockIdx.x;
    int l = threadIdx.x;
    float s  = (l < 16) ? partials[(bg*16 + l)*2]     : 0.f;
    float ss = (l < 16) ? partials[(bg*16 + l)*2 + 1] : 0.f;
#pragma unroll
    for (int off = 8; off > 0; off >>= 1) {
        s  += __shfl_down(s, off);
        ss += __shfl_down(ss, off);
    }
    if (l == 0) {
        const float inv = 1.0f / (float)(SEQ*HD);
        float mu = s * inv;
        float var = ss * inv - mu*mu;
        stats[bg*2]   = mu;
        stats[bg*2+1] = rsqrtf(var + 1e-5f);
    }
}

__global__ __launch_bounds__(256) void gn_apply(
    const float* __restrict__ proj, const float* __restrict__ stats,
    const u16* __restrict__ gamma, const u16* __restrict__ beta,
    const int* __restrict__ flag, void* __restrict__ outv)
{
    int idx = blockIdx.x * 256 + threadIdx.x;  // over B*S*D = 4M
    int d = idx & (DM-1);
    int bs = idx >> 10;
    int b = bs >> 11;
    int g = d >> 6;
    float mu   = stats[(b*NH + g)*2];
    float rstd = stats[(b*NH + g)*2 + 1];
    float v = (proj[idx] - mu) * rstd * b2f(gamma[d]) + b2f(beta[d]);
    if (*flag) ((float*)outv)[idx] = v;
    else       ((u16*)outv)[idx]   = f2b(v);
}

// ---------------- launch ----------------
extern "C" void kernel_launch(void* const* d_in, const int* in_sizes, int n_in,
                              void* d_out, int out_size, void* d_ws, size_t ws_size,
                              hipStream_t stream) {
    const void* x     = d_in[0];
    const void* Wq    = d_in[1];
    const void* bq    = d_in[2];
    const void* Wk    = d_in[3];
    const void* bk    = d_in[4];
    const void* Wv    = d_in[5];
    const void* bv    = d_in[6];
    const void* Wo    = d_in[7];
    const void* bo    = d_in[8];
    const void* gamma = d_in[9];
    const void* beta  = d_in[10];

    const size_t MB = 1024*1024;
    char* ws = (char*)d_ws;
    int*   flag     = (int*)ws;
    u16*   bqc      = (u16*)(ws + 4096);
    u16*   bkc      = (u16*)(ws + 8192);
    u16*   bvc      = (u16*)(ws + 12288);
    u16*   boc      = (u16*)(ws + 16384);
    u16*   gammac   = (u16*)(ws + 20480);
    u16*   betac    = (u16*)(ws + 24576);
    float* stats    = (float*)(ws + 28672);
    float* partials = (float*)(ws + 32768);  // 512*2 floats
    u16*   xc     = (u16*)(ws + 1*MB);    // 8 MB
    u16*   WqT    = (u16*)(ws + 9*MB);
    u16*   WkT    = (u16*)(ws + 11*MB);
    u16*   WvT    = (u16*)(ws + 13*MB);
    u16*   WoT    = (u16*)(ws + 15*MB);
    u16*   qb     = (u16*)(ws + 17*MB);   // 8 MB
    u16*   kb     = (u16*)(ws + 25*MB);   // 8 MB
    u16*   vTb    = (u16*)(ws + 33*MB);   // 8 MB
    u16*   attn   = (u16*)(ws + 41*MB);   // 8 MB
    float* proj   = (float*)(ws + 17*MB); // 16 MB, overlays qb/kb (free after retention)

    detect_dtype<<<1, 64, 0, stream>>>((const u16*)Wq, flag);
    convert_x<<<4096, 256, 0, stream>>>(x, flag, xc);
    convert_small<<<6, 256, 0, stream>>>(bq, bk, bv, bo, gamma, beta, flag,
                                         bqc, bkc, bvc, boc, gammac, betac);
    transpose4<<<dim3(32, 32, 4), 256, 0, stream>>>(Wq, Wk, Wv, Wo, flag, WqT, WkT, WvT, WoT);
    gemm_qkv<<<dim3(32, 8, 3), 256, 0, stream>>>(xc, WqT, WkT, WvT, bqc, bkc, bvc, qb, kb, vTb);
    retention<<<dim3(32, 32), 256, 0, stream>>>(qb, kb, vTb, attn);
    gemm_out<<<dim3(32, 8), 256, 0, stream>>>(attn, WoT, boc, proj);
    gn_partial<<<dim3(32, 16), 256, 0, stream>>>(proj, partials);
    gn_finalize<<<32, 64, 0, stream>>>(partials, stats);
    gn_apply<<<(SEQ*DM*2)/256, 256, 0, stream>>>(proj, stats, gammac, betac, flag, d_out);
}